// Round 2
// baseline (1252.173 us; speedup 1.0000x reference)
//
#include <hip/hip_runtime.h>
#include <hip/hip_cooperative_groups.h>
#include <hip/hip_bf16.h>
#include <cstddef>

namespace cg = cooperative_groups;

#define D 128
#define NBITS 8            // nodes per bucket = 256
#define BCAP 12288         // per-bucket region capacity (mean ~8163, +45 sigma)
#define CHUNK 4096         // edges per bucketA virtual block (256 threads)
#define TSHIFT 14          // src tile bits: 4 tiles of 16384 nodes
#define BSTRIDE8 36
// NOTE: packing (node_in_bucket<<16)|src into u32 requires N <= 65536 (here N=50000).

typedef float floatx4 __attribute__((ext_vector_type(4)));  // 4 f32
typedef float floatx2 __attribute__((ext_vector_type(2)));  // 2 f32

__device__ __forceinline__ int incl_scan64(int v) {
    const int lane = threadIdx.x & 63;
#pragma unroll
    for (int o = 1; o < 64; o <<= 1) {
        int u = __shfl_up(v, o);
        if (lane >= o) v += u;
    }
    return v;
}

__device__ __forceinline__ void accf8p(floatx2* a2, uint4 u) {
    unsigned w[4] = {u.x, u.y, u.z, u.w};
#pragma unroll
    for (int k = 0; k < 4; ++k) {
        a2[2 * k + 0] += __builtin_amdgcn_cvt_pk_f32_fp8((int)w[k], false);
        a2[2 * k + 1] += __builtin_amdgcn_cvt_pk_f32_fp8((int)w[k], true);
    }
}

__device__ __forceinline__ float dotf8(uint4 ua, uint4 ub) {
    unsigned wa[4] = {ua.x, ua.y, ua.z, ua.w};
    unsigned wb[4] = {ub.x, ub.y, ub.z, ub.w};
    float dot = 0.f;
#pragma unroll
    for (int k = 0; k < 4; ++k) {
        floatx2 alo = __builtin_amdgcn_cvt_pk_f32_fp8((int)wa[k], false);
        floatx2 ahi = __builtin_amdgcn_cvt_pk_f32_fp8((int)wa[k], true);
        floatx2 blo = __builtin_amdgcn_cvt_pk_f32_fp8((int)wb[k], false);
        floatx2 bhi = __builtin_amdgcn_cvt_pk_f32_fp8((int)wb[k], true);
        dot = fmaf(alo.x, blo.x, dot);
        dot = fmaf(alo.y, blo.y, dot);
        dot = fmaf(ahi.x, bhi.x, dot);
        dot = fmaf(ahi.y, bhi.y, dot);
    }
    return dot;
}

// =====================================================================
// ======================  COOPERATIVE MEGA KERNEL  ====================
// =====================================================================

struct MegaParams {
    const float* x;
    const int* src; const int* dst;
    const int* dia; const int* dib;
    const float* W1l; const float* b1; const float* W1r;
    const float* W2l; const float* b2; const float* W2r;
    int* bucket_cursor; float* nrm2; int* offs4; int* csr_src;
    unsigned* xf8; unsigned* h1f8; unsigned* h2f8; unsigned* Wtf8;
    unsigned* regions; unsigned* aggf8;
    float* out;
    int N, E, K, NB;
};

union alignas(16) SMem {
    struct {
        unsigned ent[CHUNK];           // 16 KB
        unsigned char bid[CHUNK];      // 4 KB
        int cnt[256], off[256], gbase[256], cur[256], tmp[256];
        int bsum[4];
    } a;                               // ~25.3 KB
    struct {
        int ndeg[1024], ncur[1024];    // 8 KB
        int bpre[256];
        int wsum4[4], bsum[4];
    } b;
    struct {
        unsigned sB[2][64 * BSTRIDE8]; // 18.4 KB
    } g;
};

// ---- phase: fp8 conversions + weight transpose + counter zeroing --------
__device__ __forceinline__ void phase_prep(const MegaParams& p) {
    const int tid = threadIdx.x;
    const int nq = p.N * (D / 4);
    const int nva = (nq + 255) >> 8;
    const int nvb = 64;                 // 4 x 4096 u32
    const int nzero = 256 + p.N;        // bucket_cursor + nrm2 (contiguous)
    const int nvc = (nzero + 255) >> 8;
    const int nv = nva + nvb + nvc;
    for (int vb = blockIdx.x; vb < nv; vb += gridDim.x) {
        if (vb < nva) {
            int t = vb * 256 + tid;
            if (t < nq) {
                float4 v = ((const float4*)p.x)[t];
                int lo = __builtin_amdgcn_cvt_pk_fp8_f32(v.x, v.y, 0, false);
                p.xf8[t] = (unsigned)__builtin_amdgcn_cvt_pk_fp8_f32(v.z, v.w, lo, true);
            }
        } else if (vb < nva + nvb) {
            int t2 = (vb - nva) * 256 + tid;   // 0..16383
            int widx = t2 >> 12;
            int within = t2 & 4095;
            int n = within >> 5;          // output col 0..127
            int g = within & 31;          // k-group of 4
            const float* W = (widx == 0) ? p.W1l : (widx == 1) ? p.W1r
                           : (widx == 2) ? p.W2l : p.W2r;
            float w0 = W[(size_t)(4 * g + 0) * D + n];
            float w1 = W[(size_t)(4 * g + 1) * D + n];
            float w2 = W[(size_t)(4 * g + 2) * D + n];
            float w3 = W[(size_t)(4 * g + 3) * D + n];
            int lo = __builtin_amdgcn_cvt_pk_fp8_f32(w0, w1, 0, false);
            p.Wtf8[(size_t)widx * 4096 + (size_t)n * 32 + g] =
                (unsigned)__builtin_amdgcn_cvt_pk_fp8_f32(w2, w3, lo, true);
        } else {
            int t3 = (vb - nva - nvb) * 256 + tid;
            if (t3 < nzero) ((int*)p.bucket_cursor)[t3] = 0;
        }
    }
}

// ---- phase: bucketize edges with LDS staging (256 thr / virtual block) --
__device__ __forceinline__ void phase_bucketA(const MegaParams& p, SMem& sm) {
    const int tid = threadIdx.x;
    const int nchunk = (p.E + CHUNK - 1) / CHUNK;
    for (int vb = blockIdx.x; vb < nchunk; vb += gridDim.x) {
        const int e0 = vb * CHUNK;
        const int n = min(CHUNK, p.E - e0);
        __syncthreads();                 // protect LDS reuse across iterations
        sm.a.cnt[tid] = 0;
        __syncthreads();
        for (int i = tid; i < n; i += 256)
            atomicAdd(&sm.a.cnt[p.dst[e0 + i] >> NBITS], 1);
        __syncthreads();
        {
            int v = sm.a.cnt[tid];
            int s = incl_scan64(v);
            if ((tid & 63) == 63) sm.a.bsum[tid >> 6] = s;
            sm.a.tmp[tid] = s;
        }
        __syncthreads();
        {
            int wv = tid >> 6;
            int add = (wv > 0 ? sm.a.bsum[0] : 0) + (wv > 1 ? sm.a.bsum[1] : 0)
                    + (wv > 2 ? sm.a.bsum[2] : 0);
            int excl = sm.a.tmp[tid] + add - sm.a.cnt[tid];
            int g = 0;
            if (tid < p.NB && sm.a.cnt[tid] > 0)
                g = atomicAdd(&p.bucket_cursor[tid], sm.a.cnt[tid]);
            sm.a.gbase[tid] = g;
            sm.a.cur[tid] = sm.a.off[tid] = excl;
        }
        __syncthreads();
        for (int i = tid; i < n; i += 256) {
            int d = p.dst[e0 + i];
            int s = p.src[e0 + i];
            int b = d >> NBITS;
            int pos = atomicAdd(&sm.a.cur[b], 1);
            sm.a.ent[pos] = ((unsigned)(d & ((1 << NBITS) - 1)) << 16) | (unsigned)s;
            sm.a.bid[pos] = (unsigned char)b;
        }
        __syncthreads();
        for (int i = tid; i < n; i += 256) {
            int b = sm.a.bid[i];
            int t = sm.a.gbase[b] + (i - sm.a.off[b]);
            if (t < BCAP) p.regions[(size_t)b * BCAP + t] = sm.a.ent[i];
        }
    }
}

// ---- phase: per-bucket hist+scatter over (node, src-tile), 256 thr ------
__device__ __forceinline__ void phase_bucketB(const MegaParams& p, SMem& sm) {
    const int tid = threadIdx.x;
    // bucket-level prefix, once per block
    {
        int v = (tid < p.NB) ? min(p.bucket_cursor[tid], BCAP) : 0;
        int s = incl_scan64(v);
        if ((tid & 63) == 63) sm.b.bsum[tid >> 6] = s;
        __syncthreads();
        int wv = tid >> 6;
        int add = (wv > 0 ? sm.b.bsum[0] : 0) + (wv > 1 ? sm.b.bsum[1] : 0)
                + (wv > 2 ? sm.b.bsum[2] : 0);
        sm.b.bpre[tid] = s + add;
        __syncthreads();
        if (blockIdx.x == 0 && tid == 0)
            p.offs4[(size_t)4 * p.N] = sm.b.bpre[255];  // total kept edges
    }
    for (int vb = blockIdx.x; vb < p.NB; vb += gridDim.x) {
        const int count = min(p.bucket_cursor[vb], BCAP);
        const int node0 = vb << NBITS;
        const unsigned* reg = p.regions + (size_t)vb * BCAP;
        const int cbase = vb ? sm.b.bpre[vb - 1] : 0;
        __syncthreads();
        *(int4*)&sm.b.ndeg[4 * tid] = make_int4(0, 0, 0, 0);
        __syncthreads();
        for (int k = tid; k < count; k += 256) {
            unsigned e = reg[k];
            int bin = (int)((e >> 16) << 2) | (int)((e & 0xffffu) >> TSHIFT);
            atomicAdd(&sm.b.ndeg[bin], 1);
        }
        __syncthreads();
        int4 d = *(const int4*)&sm.b.ndeg[4 * tid];
        int ssum = d.x + d.y + d.z + d.w;
        int inc = incl_scan64(ssum);
        if ((tid & 63) == 63) sm.b.wsum4[tid >> 6] = inc;
        __syncthreads();
        int wv = tid >> 6;
        int add = (wv > 0 ? sm.b.wsum4[0] : 0) + (wv > 1 ? sm.b.wsum4[1] : 0)
                + (wv > 2 ? sm.b.wsum4[2] : 0);
        int g0 = inc + add - ssum;
        int g1 = g0 + d.x, g2 = g1 + d.y, g3 = g2 + d.z;
        sm.b.ncur[4 * tid + 0] = g0;
        sm.b.ncur[4 * tid + 1] = g1;
        sm.b.ncur[4 * tid + 2] = g2;
        sm.b.ncur[4 * tid + 3] = g3;
        if (node0 + tid < p.N)
            *(int4*)&p.offs4[((size_t)node0 << 2) + 4 * tid] =
                make_int4(cbase + g0, cbase + g1, cbase + g2, cbase + g3);
        __syncthreads();
        for (int k = tid; k < count; k += 256) {
            unsigned e = reg[k];
            int bin = (int)((e >> 16) << 2) | (int)((e & 0xffffu) >> TSHIFT);
            int pos = atomicAdd(&sm.b.ncur[bin], 1);
            p.csr_src[cbase + pos] = (int)(e & 0xffffu);
        }
    }
}

// ---- phase: mean aggregation, fp8 -> fp8, 8 nodes/wave, 4-deep unroll ---
__device__ __forceinline__ void phase_gather(const MegaParams& p,
                                             const unsigned* __restrict__ feat8,
                                             unsigned* __restrict__ agg) {
    const int tid = threadIdx.x;
    const int wave = tid >> 6;
    const int lane = tid & 63;
    const int q = lane >> 3;
    const int l8 = lane & 7;
    const int NVW = (p.N + 7) >> 3;
    const unsigned* fb = feat8 + (size_t)l8 * 4;
    for (int vw = blockIdx.x * 4 + wave; vw < NVW; vw += gridDim.x * 4) {
        const int node = vw * 8 + q;
        const int nc = (node < p.N) ? node : (p.N - 1);
        floatx2 a2[8];
#pragma unroll
        for (int i = 0; i < 8; ++i) a2[i] = (floatx2)(0.f);
        int4 ob = *(const int4*)(p.offs4 + ((size_t)nc << 2));
        const int oend = p.offs4[((size_t)nc << 2) + 4];
        const int bounds[5] = {ob.x, ob.y, ob.z, ob.w, oend};
#pragma unroll
        for (int t = 0; t < 4; ++t) {
            int e = bounds[t];
            const int se = bounds[t + 1];
            for (; e + 4 <= se; e += 4) {
                int s0 = p.csr_src[e];
                int s1 = p.csr_src[e + 1];
                int s2 = p.csr_src[e + 2];
                int s3 = p.csr_src[e + 3];
                uint4 u0 = *(const uint4*)(fb + (size_t)s0 * 32);
                uint4 u1 = *(const uint4*)(fb + (size_t)s1 * 32);
                uint4 u2 = *(const uint4*)(fb + (size_t)s2 * 32);
                uint4 u3 = *(const uint4*)(fb + (size_t)s3 * 32);
                accf8p(a2, u0); accf8p(a2, u1); accf8p(a2, u2); accf8p(a2, u3);
            }
            for (; e + 2 <= se; e += 2) {
                int s0 = p.csr_src[e];
                int s1 = p.csr_src[e + 1];
                uint4 u0 = *(const uint4*)(fb + (size_t)s0 * 32);
                uint4 u1 = *(const uint4*)(fb + (size_t)s1 * 32);
                accf8p(a2, u0); accf8p(a2, u1);
            }
            if (e < se) {
                int s0 = p.csr_src[e];
                uint4 u0 = *(const uint4*)(fb + (size_t)s0 * 32);
                accf8p(a2, u0);
            }
        }
        float r = 1.0f / fmaxf((float)(oend - bounds[0]), 1.0f);
        unsigned o[4];
#pragma unroll
        for (int j = 0; j < 4; ++j) {
            int lo = __builtin_amdgcn_cvt_pk_fp8_f32(a2[2 * j].x * r, a2[2 * j].y * r, 0, false);
            o[j] = (unsigned)__builtin_amdgcn_cvt_pk_fp8_f32(a2[2 * j + 1].x * r,
                                                             a2[2 * j + 1].y * r, lo, true);
        }
        if (node < p.N) {
            *(uint4*)(agg + (size_t)node * 32 + l8 * 4) = make_uint4(o[0], o[1], o[2], o[3]);
        }
    }
}

// ---- phase: MFMA GEMM, all-fp8, column-split x2, LDS-staged weights -----
__device__ __forceinline__ void phase_gemm(const MegaParams& p, SMem& sm,
        const unsigned* __restrict__ agg, const unsigned* __restrict__ xin,
        const unsigned* __restrict__ Wlt, const unsigned* __restrict__ Wrt,
        const float* __restrict__ bias, unsigned char* __restrict__ out8,
        float* __restrict__ nrm2, int relu) {
    const int tid = threadIdx.x;
    const int wave = tid >> 6;
    const int lane = tid & 63;
    const int li = lane & 15;
    const int quad = lane >> 4;
    const int NVB = ((p.N + 63) >> 6) * 2;
    for (int vb = blockIdx.x; vb < NVB; vb += gridDim.x) {
        const int bx = vb >> 1;
        const int by = vb & 1;
        const int colbase = by * 64;
        __syncthreads();                 // protect sB reuse across iterations
#pragma unroll
        for (int m = 0; m < 2; ++m) {
            const unsigned* Wsrc = (m ? Wrt : Wlt) + (size_t)colbase * 32;
            for (int i = tid; i < 512; i += 256) {
                int col = i >> 3;
                int c4 = (i & 7) * 4;
                *(uint4*)(&sm.g.sB[m][col * BSTRIDE8 + c4]) =
                    *(const uint4*)(Wsrc + col * 32 + c4);
            }
        }
        __syncthreads();
        const int node0 = bx * 64 + wave * 16;
        if (node0 >= p.N) continue;      // converges at next loop-top barrier

        floatx4 acc[4];
#pragma unroll
        for (int t = 0; t < 4; ++t) acc[t] = (floatx4)(0.f);

        int arow = node0 + li;
        if (arow >= p.N) arow = p.N - 1;  // clamp; stores are guarded
        const unsigned* aptr1 = agg + (size_t)arow * 32 + quad * 2;
        const unsigned* aptr2 = xin + (size_t)arow * 32 + quad * 2;
        const unsigned* sb0 = &sm.g.sB[0][li * BSTRIDE8 + quad * 2];
        const unsigned* sb1 = &sm.g.sB[1][li * BSTRIDE8 + quad * 2];

#pragma unroll
        for (int ks = 0; ks < 4; ++ks) {
            long af = *(const long*)(aptr1 + ks * 8);
#pragma unroll
            for (int ct = 0; ct < 4; ++ct) {
                long bf = *(const long*)(sb0 + ct * 16 * BSTRIDE8 + ks * 8);
                acc[ct] = __builtin_amdgcn_mfma_f32_16x16x32_fp8_fp8(af, bf, acc[ct], 0, 0, 0);
            }
        }
#pragma unroll
        for (int ks = 0; ks < 4; ++ks) {
            long af = *(const long*)(aptr2 + ks * 8);
#pragma unroll
            for (int ct = 0; ct < 4; ++ct) {
                long bf = *(const long*)(sb1 + ct * 16 * BSTRIDE8 + ks * 8);
                acc[ct] = __builtin_amdgcn_mfma_f32_16x16x32_fp8_fp8(af, bf, acc[ct], 0, 0, 0);
            }
        }

        float sq[4] = {0.f, 0.f, 0.f, 0.f};
#pragma unroll
        for (int ct = 0; ct < 4; ++ct) {
            int col = colbase + ct * 16 + li;
            float bv = bias[col];
#pragma unroll
            for (int r = 0; r < 4; ++r) {
                int node = node0 + quad * 4 + r;
                float o = acc[ct][r] + bv;
                if (relu) o = fmaxf(o, 0.f);
                int pk = __builtin_amdgcn_cvt_pk_fp8_f32(o, o, 0, false);
                if (nrm2) {
                    floatx2 dq = __builtin_amdgcn_cvt_pk_f32_fp8(pk, false);
                    sq[r] += dq.x * dq.x;
                }
                if (node < p.N) {
                    out8[(size_t)node * D + col] = (unsigned char)(pk & 0xff);
                }
            }
        }
        if (nrm2) {
#pragma unroll
            for (int r = 0; r < 4; ++r) {
                float s = sq[r];
                s += __shfl_xor(s, 1);
                s += __shfl_xor(s, 2);
                s += __shfl_xor(s, 4);
                s += __shfl_xor(s, 8);
                int node = node0 + quad * 4 + r;
                if (li == 0 && node < p.N) unsafeAtomicAdd(&nrm2[node], s);
            }
        }
    }
}

// ---- phase: decode, 8 lanes/pair, 2-pair unroll -------------------------
__device__ __forceinline__ void phase_decode(const MegaParams& p) {
    const int tid = threadIdx.x;
    const int l8 = tid & 7;
    const int g0 = (blockIdx.x * 256 + tid) >> 3;
    const int ng = gridDim.x * 32;       // 8-lane groups per stride
    for (int pb = g0; pb < p.K; pb += 2 * ng) {
        const int pA = pb;
        const int pB = pb + ng;
        const bool hasB = (pB < p.K);
        int a0 = p.dia[pA];
        int a1 = p.dib[pA];
        uint4 uA0 = *(const uint4*)(p.h2f8 + (size_t)a0 * 32 + l8 * 4);
        uint4 uA1 = *(const uint4*)(p.h2f8 + (size_t)a1 * 32 + l8 * 4);
        int b0 = 0, b1 = 0;
        uint4 uB0 = uA0, uB1 = uA1;
        if (hasB) {
            b0 = p.dia[pB];
            b1 = p.dib[pB];
            uB0 = *(const uint4*)(p.h2f8 + (size_t)b0 * 32 + l8 * 4);
            uB1 = *(const uint4*)(p.h2f8 + (size_t)b1 * 32 + l8 * 4);
        }
        float dotA = dotf8(uA0, uA1);
        dotA += __shfl_xor(dotA, 1);
        dotA += __shfl_xor(dotA, 2);
        dotA += __shfl_xor(dotA, 4);
        if (l8 == 0) {
            float denom = fmaxf(sqrtf(p.nrm2[a0] * p.nrm2[a1]), 1e-6f);
            float s = dotA / denom;
            p.out[pA] = 1.0f / (1.0f + expf(-s));
        }
        if (hasB) {
            float dotB = dotf8(uB0, uB1);
            dotB += __shfl_xor(dotB, 1);
            dotB += __shfl_xor(dotB, 2);
            dotB += __shfl_xor(dotB, 4);
            if (l8 == 0) {
                float denom = fmaxf(sqrtf(p.nrm2[b0] * p.nrm2[b1]), 1e-6f);
                float s = dotB / denom;
                p.out[pB] = 1.0f / (1.0f + expf(-s));
            }
        }
    }
}

__global__ void __launch_bounds__(256, 4) mega_kernel(MegaParams p) {
    __shared__ SMem sm;
    cg::grid_group grid = cg::this_grid();

    phase_prep(p);
    __threadfence(); grid.sync(); __threadfence();

    phase_bucketA(p, sm);
    __threadfence(); grid.sync(); __threadfence();

    phase_bucketB(p, sm);
    __threadfence(); grid.sync(); __threadfence();

    phase_gather(p, p.xf8, p.aggf8);
    __threadfence(); grid.sync(); __threadfence();

    phase_gemm(p, sm, p.aggf8, p.xf8, p.Wtf8, p.Wtf8 + 4096, p.b1,
               (unsigned char*)p.h1f8, nullptr, 1);
    __threadfence(); grid.sync(); __threadfence();

    phase_gather(p, p.h1f8, p.aggf8);
    __threadfence(); grid.sync(); __threadfence();

    phase_gemm(p, sm, p.aggf8, p.h1f8, p.Wtf8 + 8192, p.Wtf8 + 12288, p.b2,
               (unsigned char*)p.h2f8, p.nrm2, 0);
    __threadfence(); grid.sync(); __threadfence();

    phase_decode(p);
}

// =====================================================================
// =================  FALLBACK: separate-kernel pipeline  ==============
// =====================================================================

__global__ void prep_kernel(const float* __restrict__ x, unsigned* __restrict__ xf8,
                            int nq, int nblk_a, int nblk_b,
                            const float* __restrict__ W1l, const float* __restrict__ W1r,
                            const float* __restrict__ W2l, const float* __restrict__ W2r,
                            unsigned* __restrict__ Wtf8, int* __restrict__ zero_base,
                            int nzero) {
    int blk = (int)blockIdx.x;
    if (blk < nblk_a) {
        int t = blk * 256 + threadIdx.x;
        if (t < nq) {
            float4 v = ((const float4*)x)[t];
            int lo = __builtin_amdgcn_cvt_pk_fp8_f32(v.x, v.y, 0, false);
            xf8[t] = (unsigned)__builtin_amdgcn_cvt_pk_fp8_f32(v.z, v.w, lo, true);
        }
    } else if (blk < nblk_a + nblk_b) {
        int t2 = (blk - nblk_a) * 256 + threadIdx.x;
        int widx = t2 >> 12;
        int within = t2 & 4095;
        int n = within >> 5;
        int g = within & 31;
        const float* W = (widx == 0) ? W1l : (widx == 1) ? W1r : (widx == 2) ? W2l : W2r;
        float w0 = W[(size_t)(4 * g + 0) * D + n];
        float w1 = W[(size_t)(4 * g + 1) * D + n];
        float w2 = W[(size_t)(4 * g + 2) * D + n];
        float w3 = W[(size_t)(4 * g + 3) * D + n];
        int lo = __builtin_amdgcn_cvt_pk_fp8_f32(w0, w1, 0, false);
        Wtf8[(size_t)widx * 4096 + (size_t)n * 32 + g] =
            (unsigned)__builtin_amdgcn_cvt_pk_fp8_f32(w2, w3, lo, true);
    } else {
        int t3 = (blk - nblk_a - nblk_b) * 256 + threadIdx.x;
        if (t3 < nzero) zero_base[t3] = 0;
    }
}

__global__ void __launch_bounds__(512) bucketA_kernel(
        const int* __restrict__ src, const int* __restrict__ dst,
        int* __restrict__ bucket_cursor, unsigned* __restrict__ regions,
        int n_edges, int n_buckets) {
    __shared__ int cnt[256];
    __shared__ int off[256];
    __shared__ int gbase[256];
    __shared__ int cur[256];
    __shared__ int tmp[256];
    __shared__ int bsum[4];
    __shared__ unsigned ent[CHUNK];
    __shared__ unsigned char bid[CHUNK];
    const int tid = threadIdx.x;
    const int e0 = blockIdx.x * CHUNK;
    const int n = min(CHUNK, n_edges - e0);

    if (tid < 256) cnt[tid] = 0;
    __syncthreads();
    for (int i = tid; i < n; i += 512) {
        atomicAdd(&cnt[dst[e0 + i] >> NBITS], 1);
    }
    __syncthreads();
    if (tid < 256) {
        int v = cnt[tid];
        int s = incl_scan64(v);
        if ((tid & 63) == 63) bsum[tid >> 6] = s;
        tmp[tid] = s;
    }
    __syncthreads();
    if (tid < 256) {
        int wv = tid >> 6;
        int add = (wv > 0 ? bsum[0] : 0) + (wv > 1 ? bsum[1] : 0) + (wv > 2 ? bsum[2] : 0);
        int excl = tmp[tid] + add - cnt[tid];
        if (tid < n_buckets && cnt[tid] > 0) gbase[tid] = atomicAdd(&bucket_cursor[tid], cnt[tid]);
        else gbase[tid] = 0;
        cur[tid] = off[tid] = excl;
    }
    __syncthreads();
    for (int i = tid; i < n; i += 512) {
        int d = dst[e0 + i];
        int s = src[e0 + i];
        int b = d >> NBITS;
        int p = atomicAdd(&cur[b], 1);
        ent[p] = ((unsigned)(d & ((1 << NBITS) - 1)) << 16) | (unsigned)s;
        bid[p] = (unsigned char)b;
    }
    __syncthreads();
    for (int i = tid; i < n; i += 512) {
        int b = bid[i];
        int t = gbase[b] + (i - off[b]);
        if (t < BCAP) regions[(size_t)b * BCAP + t] = ent[i];
    }
}

__global__ void __launch_bounds__(1024) bucketB_kernel(
        const unsigned* __restrict__ regions, const int* __restrict__ bucket_cursor,
        int* __restrict__ offs4, int* __restrict__ csr_src,
        int n_buckets, int n_nodes) {
    __shared__ int ndeg[1024];
    __shared__ int ncur[1024];
    __shared__ int tmp[256];
    __shared__ int wsum[16];
    __shared__ int bsum[4];
    __shared__ int s_cbase;
    const int b = blockIdx.x;
    const int tid = threadIdx.x;
    const int count = min(bucket_cursor[b], BCAP);
    const int node0 = b << NBITS;
    const unsigned* reg = regions + (size_t)b * BCAP;

    if (tid < 256) {
        int v = (tid < n_buckets) ? min(bucket_cursor[tid], BCAP) : 0;
        int s = incl_scan64(v);
        if ((tid & 63) == 63) bsum[tid >> 6] = s;
        tmp[tid] = s;
    }
    ndeg[tid] = 0;
    __syncthreads();
    if (tid < 256) {
        int wv = tid >> 6;
        int add = (wv > 0 ? bsum[0] : 0) + (wv > 1 ? bsum[1] : 0) + (wv > 2 ? bsum[2] : 0);
        tmp[tid] += add;
    }
    __syncthreads();
    if (tid == 0) {
        s_cbase = b ? tmp[b - 1] : 0;
        if (b == 0) offs4[(size_t)4 * n_nodes] = tmp[255];
    }
    __syncthreads();

    for (int k = tid; k < count; k += 1024) {
        unsigned e = reg[k];
        int bin = (int)((e >> 16) << 2) | (int)((e & 0xffffu) >> TSHIFT);
        atomicAdd(&ndeg[bin], 1);
    }
    __syncthreads();
    {
        int v = ndeg[tid];
        int s = incl_scan64(v);
        const int wid = tid >> 6;
        if ((tid & 63) == 63) wsum[wid] = s;
        __syncthreads();
        if (tid < 16) {
            int wv = wsum[tid];
#pragma unroll
            for (int o = 1; o < 16; o <<= 1) {
                int u = __shfl_up(wv, o);
                if (tid >= o) wv += u;
            }
            wsum[tid] = wv;
        }
        __syncthreads();
        const int cbase = s_cbase;
        int excl = s + (wid ? wsum[wid - 1] : 0) - v;
        ncur[tid] = excl;
        if (node0 + (tid >> 2) < n_nodes) offs4[(node0 << 2) + tid] = cbase + excl;
    }
    __syncthreads();
    const int cbase = s_cbase;
    for (int k = tid; k < count; k += 1024) {
        unsigned e = reg[k];
        int bin = (int)((e >> 16) << 2) | (int)((e & 0xffffu) >> TSHIFT);
        int p = atomicAdd(&ncur[bin], 1);
        csr_src[cbase + p] = (int)(e & 0xffffu);
    }
}

__global__ void __launch_bounds__(256, 8) gather_kernel(
        const unsigned* __restrict__ feat8,
        const int* __restrict__ offs4,
        const int* __restrict__ csr_src,
        unsigned* __restrict__ aggf8, int n_nodes) {
    const int wid = (blockIdx.x * blockDim.x + threadIdx.x) >> 6;
    const int lane = threadIdx.x & 63;
    const int q = lane >> 3;
    const int l8 = lane & 7;
    const int node = wid * 8 + q;
    const int nc = (node < n_nodes) ? node : (n_nodes - 1);
    const unsigned* fb = feat8 + (size_t)l8 * 4;
    floatx2 a2[8];
#pragma unroll
    for (int i = 0; i < 8; ++i) a2[i] = (floatx2)(0.f);

    int4 ob = *(const int4*)(offs4 + (size_t)4 * nc);
    const int oend = offs4[(size_t)4 * nc + 4];
    const int bnd0 = ob.x, bnd1 = ob.y, bnd2 = ob.z, bnd3 = ob.w;
#pragma unroll
    for (int t = 0; t < 4; ++t) {
        int e = (t == 0) ? bnd0 : (t == 1) ? bnd1 : (t == 2) ? bnd2 : bnd3;
        const int se = (t == 0) ? bnd1 : (t == 1) ? bnd2 : (t == 2) ? bnd3 : oend;
        for (; e + 2 <= se; e += 2) {
            int s0 = csr_src[e];
            int s1 = csr_src[e + 1];
            uint4 u0 = *(const uint4*)(fb + (size_t)s0 * 32);
            uint4 u1 = *(const uint4*)(fb + (size_t)s1 * 32);
            accf8p(a2, u0);
            accf8p(a2, u1);
        }
        if (e < se) {
            int s0 = csr_src[e];
            uint4 u0 = *(const uint4*)(fb + (size_t)s0 * 32);
            accf8p(a2, u0);
        }
    }

    float r = 1.0f / fmaxf((float)(oend - bnd0), 1.0f);
    unsigned o[4];
#pragma unroll
    for (int j = 0; j < 4; ++j) {
        int lo = __builtin_amdgcn_cvt_pk_fp8_f32(a2[2 * j].x * r, a2[2 * j].y * r, 0, false);
        o[j] = (unsigned)__builtin_amdgcn_cvt_pk_fp8_f32(a2[2 * j + 1].x * r,
                                                         a2[2 * j + 1].y * r, lo, true);
    }
    if (node < n_nodes) {
        *(uint4*)(aggf8 + (size_t)node * 32 + l8 * 4) = make_uint4(o[0], o[1], o[2], o[3]);
    }
}

__global__ void __launch_bounds__(256, 4) mfma_gemm(
        const unsigned* __restrict__ aggf8, const unsigned* __restrict__ xin8,
        const unsigned* __restrict__ Wlt, const unsigned* __restrict__ Wrt,
        const float* __restrict__ bias, unsigned char* __restrict__ outf8,
        float* __restrict__ nrm2, int n_nodes, int relu) {
    __shared__ unsigned sB[2][64 * BSTRIDE8];
    const int tid = threadIdx.x;
    const int wave = tid >> 6;
    const int lane = tid & 63;
    const int li = lane & 15;
    const int quad = lane >> 4;
    const int node0 = blockIdx.x * 64 + wave * 16;
    const int colbase = blockIdx.y * 64;

#pragma unroll
    for (int m = 0; m < 2; ++m) {
        const unsigned* Wsrc = (m ? Wrt : Wlt) + (size_t)colbase * 32;
        for (int i = tid; i < 512; i += 256) {
            int col = i >> 3;
            int c4 = (i & 7) * 4;
            uint4 v = *(const uint4*)(Wsrc + col * 32 + c4);
            *(uint4*)(&sB[m][col * BSTRIDE8 + c4]) = v;
        }
    }
    __syncthreads();

    if (node0 >= n_nodes) return;

    floatx4 acc[4];
#pragma unroll
    for (int t = 0; t < 4; ++t) acc[t] = (floatx4)(0.f);

    int arow = node0 + li;
    if (arow >= n_nodes) arow = n_nodes - 1;
    const unsigned* aptr1 = aggf8 + (size_t)arow * 32 + quad * 2;
    const unsigned* aptr2 = xin8 + (size_t)arow * 32 + quad * 2;
    const unsigned* sb0 = &sB[0][li * BSTRIDE8 + quad * 2];
    const unsigned* sb1 = &sB[1][li * BSTRIDE8 + quad * 2];

#pragma unroll
    for (int ks = 0; ks < 4; ++ks) {
        long af = *(const long*)(aptr1 + ks * 8);
#pragma unroll
        for (int ct = 0; ct < 4; ++ct) {
            long bf = *(const long*)(sb0 + ct * 16 * BSTRIDE8 + ks * 8);
            acc[ct] = __builtin_amdgcn_mfma_f32_16x16x32_fp8_fp8(af, bf, acc[ct], 0, 0, 0);
        }
    }
#pragma unroll
    for (int ks = 0; ks < 4; ++ks) {
        long af = *(const long*)(aptr2 + ks * 8);
#pragma unroll
        for (int ct = 0; ct < 4; ++ct) {
            long bf = *(const long*)(sb1 + ct * 16 * BSTRIDE8 + ks * 8);
            acc[ct] = __builtin_amdgcn_mfma_f32_16x16x32_fp8_fp8(af, bf, acc[ct], 0, 0, 0);
        }
    }

    float sq[4] = {0.f, 0.f, 0.f, 0.f};
#pragma unroll
    for (int ct = 0; ct < 4; ++ct) {
        int col = colbase + ct * 16 + li;
        float bv = bias[col];
#pragma unroll
        for (int r = 0; r < 4; ++r) {
            int node = node0 + quad * 4 + r;
            float o = acc[ct][r] + bv;
            if (relu) o = fmaxf(o, 0.f);
            int pk = __builtin_amdgcn_cvt_pk_fp8_f32(o, o, 0, false);
            if (nrm2) {
                floatx2 dq = __builtin_amdgcn_cvt_pk_f32_fp8(pk, false);
                sq[r] += dq.x * dq.x;
            }
            if (node < n_nodes) {
                outf8[(size_t)node * D + col] = (unsigned char)(pk & 0xff);
            }
        }
    }
    if (nrm2) {
#pragma unroll
        for (int r = 0; r < 4; ++r) {
            float s = sq[r];
            s += __shfl_xor(s, 1);
            s += __shfl_xor(s, 2);
            s += __shfl_xor(s, 4);
            s += __shfl_xor(s, 8);
            int node = node0 + quad * 4 + r;
            if (li == 0 && node < n_nodes) unsafeAtomicAdd(&nrm2[node], s);
        }
    }
}

__global__ void decode_kernel(const unsigned* __restrict__ h8, const float* __restrict__ nrm2,
                              const int* __restrict__ ia, const int* __restrict__ ib,
                              float* __restrict__ out, int n_pairs) {
    int t = blockIdx.x * blockDim.x + threadIdx.x;
    int p = t >> 3;
    if (p >= n_pairs) return;
    int l8 = t & 7;
    int i0 = ia[p];
    int i1 = ib[p];
    uint4 ua = *(const uint4*)(h8 + (size_t)i0 * 32 + l8 * 4);
    uint4 ub = *(const uint4*)(h8 + (size_t)i1 * 32 + l8 * 4);
    float dot = dotf8(ua, ub);
    dot += __shfl_xor(dot, 1);
    dot += __shfl_xor(dot, 2);
    dot += __shfl_xor(dot, 4);
    if (l8 == 0) {
        float denom = fmaxf(sqrtf(nrm2[i0] * nrm2[i1]), 1e-6f);
        float s = dot / denom;
        out[p] = 1.0f / (1.0f + expf(-s));
    }
}

// =====================================================================

extern "C" void kernel_launch(void* const* d_in, const int* in_sizes, int n_in,
                              void* d_out, int out_size, void* d_ws, size_t ws_size,
                              hipStream_t stream) {
    const float* x   = (const float*)d_in[0];
    const int*   ei  = (const int*)d_in[1];
    const int*   di  = (const int*)d_in[2];
    const float* W1l = (const float*)d_in[3];
    const float* b1  = (const float*)d_in[4];
    const float* W1r = (const float*)d_in[5];
    const float* W2l = (const float*)d_in[6];
    const float* b2  = (const float*)d_in[7];
    const float* W2r = (const float*)d_in[8];

    const int N = in_sizes[0] / D;
    const int E = in_sizes[1] / 2;
    const int K = in_sizes[2] / 2;
    const size_t NQ = (size_t)N * (D / 4);
    const int NB = (N + 255) >> 8;

    const int* src  = ei;
    const int* dstp = ei + E;
    const int* dia  = di;
    const int* dib  = di + K;

    // ---- workspace layout (u32 units) ----
    int* bucket_cursor = (int*)d_ws;                    // 256 (zeroed in prep)
    float* nrm2        = (float*)(bucket_cursor + 256); // N   (zeroed in prep)
    int* offs4         = (int*)(nrm2 + N);              // 4N+64
    int* csr_src       = offs4 + 4 * N + 64;            // E
    unsigned* xf8      = (unsigned*)(csr_src + E);      // NQ
    unsigned* h1f8     = xf8 + NQ;                      // NQ
    unsigned* h2f8     = h1f8 + NQ;                     // NQ
    unsigned* Wtf8     = h2f8 + NQ;                     // 4 x 4096
    unsigned* regions  = Wtf8 + 16384;                  // NB*BCAP (aggf8 overlays)
    unsigned* aggf8    = regions;

    float* out = (float*)d_out;

    MegaParams P;
    P.x = x; P.src = src; P.dst = dstp; P.dia = dia; P.dib = dib;
    P.W1l = W1l; P.b1 = b1; P.W1r = W1r; P.W2l = W2l; P.b2 = b2; P.W2r = W2r;
    P.bucket_cursor = bucket_cursor; P.nrm2 = nrm2; P.offs4 = offs4; P.csr_src = csr_src;
    P.xf8 = xf8; P.h1f8 = h1f8; P.h2f8 = h2f8; P.Wtf8 = Wtf8;
    P.regions = regions; P.aggf8 = aggf8;
    P.out = out;
    P.N = N; P.E = E; P.K = K; P.NB = NB;

    static int s_grid = 0;
    if (s_grid == 0) {
        hipDeviceProp_t prop{};
        (void)hipGetDeviceProperties(&prop, 0);
        int ncu = (prop.multiProcessorCount > 0) ? prop.multiProcessorCount : 256;
        int bpc = 0;
        hipError_t oe = hipOccupancyMaxActiveBlocksPerMultiprocessor(&bpc, mega_kernel, 256, 0);
        if (oe != hipSuccess || bpc < 1) bpc = 1;
        if (bpc > 4) bpc = 4;
        s_grid = ncu * bpc;
    }

    void* args[] = {(void*)&P};
    hipError_t err = hipLaunchCooperativeKernel(mega_kernel, dim3(s_grid), dim3(256),
                                                args, 0u, stream);
    if (err == hipSuccess) return;

    // ---- fallback: separate-kernel pipeline (round-1 verified) ----
    const int nq = (int)NQ;
    const int nblk_a = (nq + 255) / 256;
    const int nblk_b = 64;
    const int nzero = 256 + N;
    const int nblk_c = (nzero + 255) / 256;
    prep_kernel<<<nblk_a + nblk_b + nblk_c, 256, 0, stream>>>(
        x, xf8, nq, nblk_a, nblk_b, W1l, W1r, W2l, W2r, Wtf8, bucket_cursor, nzero);

    const int gridA = (E + CHUNK - 1) / CHUNK;
    bucketA_kernel<<<gridA, 512, 0, stream>>>(src, dstp, bucket_cursor, regions, E, NB);
    bucketB_kernel<<<NB, 1024, 0, stream>>>(regions, bucket_cursor, offs4, csr_src, NB, N);

    const int gather_waves = (N + 7) / 8;
    const int gather_blocks = (gather_waves * 64 + 255) / 256;
    const dim3 gemm_grid((N + 63) / 64, 2);

    gather_kernel<<<gather_blocks, 256, 0, stream>>>(xf8, offs4, csr_src, aggf8, N);
    mfma_gemm<<<gemm_grid, 256, 0, stream>>>(aggf8, xf8, Wtf8, Wtf8 + 4096, b1,
                                             (unsigned char*)h1f8, nullptr, N, 1);

    gather_kernel<<<gather_blocks, 256, 0, stream>>>(h1f8, offs4, csr_src, aggf8, N);
    mfma_gemm<<<gemm_grid, 256, 0, stream>>>(aggf8, h1f8, Wtf8 + 8192, Wtf8 + 12288, b2,
                                             (unsigned char*)h2f8, nrm2, N, 0);

    {
        long long threads = (long long)K * 8;
        int blocks = (int)((threads + 255) / 256);
        decode_kernel<<<blocks, 256, 0, stream>>>(h2f8, nrm2, dia, dib, out, K);
    }
}

// Round 3
// 261.764 us; speedup vs baseline: 4.7836x; 4.7836x over previous
//
#include <hip/hip_runtime.h>
#include <hip/hip_bf16.h>
#include <cstddef>

#define D 128
#define NBITS 8            // nodes per bucket = 256
#define BCAP 12288         // per-bucket region capacity (mean ~8163, +45 sigma)
#define CHUNK 4096         // edges per bucketA workgroup (512 threads)
#define TSHIFT 14          // src tile bits (bucketB bin ordering; harmless now)
#define BSTRIDE8 36
// NOTE: packing (node_in_bucket<<16)|src into u32 requires N <= 65536 (here N=50000).

typedef float floatx4 __attribute__((ext_vector_type(4)));  // 4 f32
typedef float floatx2 __attribute__((ext_vector_type(2)));  // 2 f32

__device__ __forceinline__ int incl_scan64(int v) {
    const int lane = threadIdx.x & 63;
#pragma unroll
    for (int o = 1; o < 64; o <<= 1) {
        int u = __shfl_up(v, o);
        if (lane >= o) v += u;
    }
    return v;
}

__device__ __forceinline__ void accf8p(floatx2* a2, uint4 u) {
    unsigned w[4] = {u.x, u.y, u.z, u.w};
#pragma unroll
    for (int k = 0; k < 4; ++k) {
        a2[2 * k + 0] += __builtin_amdgcn_cvt_pk_f32_fp8((int)w[k], false);
        a2[2 * k + 1] += __builtin_amdgcn_cvt_pk_f32_fp8((int)w[k], true);
    }
}

__device__ __forceinline__ float dotf8(uint4 ua, uint4 ub) {
    unsigned wa[4] = {ua.x, ua.y, ua.z, ua.w};
    unsigned wb[4] = {ub.x, ub.y, ub.z, ub.w};
    float dot = 0.f;
#pragma unroll
    for (int k = 0; k < 4; ++k) {
        floatx2 alo = __builtin_amdgcn_cvt_pk_f32_fp8((int)wa[k], false);
        floatx2 ahi = __builtin_amdgcn_cvt_pk_f32_fp8((int)wa[k], true);
        floatx2 blo = __builtin_amdgcn_cvt_pk_f32_fp8((int)wb[k], false);
        floatx2 bhi = __builtin_amdgcn_cvt_pk_f32_fp8((int)wb[k], true);
        dot = fmaf(alo.x, blo.x, dot);
        dot = fmaf(alo.y, blo.y, dot);
        dot = fmaf(ahi.x, bhi.x, dot);
        dot = fmaf(ahi.y, bhi.y, dot);
    }
    return dot;
}

// ---- fused prep: x f32 -> fp8; 4x W -> Wt fp8 [n][k]; zero counters -----
__global__ void prep_kernel(const float* __restrict__ x, unsigned* __restrict__ xf8,
                            int nq, int nblk_a, int nblk_b,
                            const float* __restrict__ W1l, const float* __restrict__ W1r,
                            const float* __restrict__ W2l, const float* __restrict__ W2r,
                            unsigned* __restrict__ Wtf8, int* __restrict__ zero_base,
                            int nzero) {
    int blk = (int)blockIdx.x;
    if (blk < nblk_a) {
        int t = blk * 256 + threadIdx.x;
        if (t < nq) {
            float4 v = ((const float4*)x)[t];
            int lo = __builtin_amdgcn_cvt_pk_fp8_f32(v.x, v.y, 0, false);
            xf8[t] = (unsigned)__builtin_amdgcn_cvt_pk_fp8_f32(v.z, v.w, lo, true);
        }
    } else if (blk < nblk_a + nblk_b) {
        int t2 = (blk - nblk_a) * 256 + threadIdx.x;   // 0..16383
        int widx = t2 >> 12;
        int within = t2 & 4095;
        int n = within >> 5;          // output col 0..127
        int g = within & 31;          // k-group of 4
        const float* W = (widx == 0) ? W1l : (widx == 1) ? W1r : (widx == 2) ? W2l : W2r;
        float w0 = W[(size_t)(4 * g + 0) * D + n];
        float w1 = W[(size_t)(4 * g + 1) * D + n];
        float w2 = W[(size_t)(4 * g + 2) * D + n];
        float w3 = W[(size_t)(4 * g + 3) * D + n];
        int lo = __builtin_amdgcn_cvt_pk_fp8_f32(w0, w1, 0, false);
        Wtf8[(size_t)widx * 4096 + (size_t)n * 32 + g] =
            (unsigned)__builtin_amdgcn_cvt_pk_fp8_f32(w2, w3, lo, true);
    } else {
        int t3 = (blk - nblk_a - nblk_b) * 256 + threadIdx.x;
        if (t3 < nzero) zero_base[t3] = 0;
    }
}

// ---- CSR build pass A: bucketize edges with LDS staging (512 thr) -------
__global__ void __launch_bounds__(512) bucketA_kernel(
        const int* __restrict__ src, const int* __restrict__ dst,
        int* __restrict__ bucket_cursor, unsigned* __restrict__ regions,
        int n_edges, int n_buckets) {
    __shared__ int cnt[256];
    __shared__ int off[256];
    __shared__ int gbase[256];
    __shared__ int cur[256];
    __shared__ int tmp[256];
    __shared__ int bsum[4];
    __shared__ unsigned ent[CHUNK];
    __shared__ unsigned char bid[CHUNK];
    const int tid = threadIdx.x;
    const int e0 = blockIdx.x * CHUNK;
    const int n = min(CHUNK, n_edges - e0);

    if (tid < 256) cnt[tid] = 0;
    __syncthreads();
    for (int i = tid; i < n; i += 512) {
        atomicAdd(&cnt[dst[e0 + i] >> NBITS], 1);
    }
    __syncthreads();
    if (tid < 256) {
        int v = cnt[tid];
        int s = incl_scan64(v);
        if ((tid & 63) == 63) bsum[tid >> 6] = s;
        tmp[tid] = s;
    }
    __syncthreads();
    if (tid < 256) {
        int wv = tid >> 6;
        int add = (wv > 0 ? bsum[0] : 0) + (wv > 1 ? bsum[1] : 0) + (wv > 2 ? bsum[2] : 0);
        int excl = tmp[tid] + add - cnt[tid];
        if (tid < n_buckets && cnt[tid] > 0) gbase[tid] = atomicAdd(&bucket_cursor[tid], cnt[tid]);
        else gbase[tid] = 0;
        cur[tid] = off[tid] = excl;
    }
    __syncthreads();
    for (int i = tid; i < n; i += 512) {
        int d = dst[e0 + i];
        int s = src[e0 + i];
        int b = d >> NBITS;
        int p = atomicAdd(&cur[b], 1);
        ent[p] = ((unsigned)(d & ((1 << NBITS) - 1)) << 16) | (unsigned)s;
        bid[p] = (unsigned char)b;
    }
    __syncthreads();
    for (int i = tid; i < n; i += 512) {
        int b = bid[i];
        int t = gbase[b] + (i - off[b]);
        if (t < BCAP) regions[(size_t)b * BCAP + t] = ent[i];
    }
}

// ---- CSR build pass B: per-bucket hist+scatter over (node, src-tile) ----
__global__ void __launch_bounds__(1024) bucketB_kernel(
        const unsigned* __restrict__ regions, const int* __restrict__ bucket_cursor,
        int* __restrict__ offs4, int* __restrict__ csr_src,
        int n_buckets, int n_nodes) {
    __shared__ int ndeg[1024];
    __shared__ int ncur[1024];
    __shared__ int tmp[256];
    __shared__ int wsum[16];
    __shared__ int bsum[4];
    __shared__ int s_cbase;
    const int b = blockIdx.x;
    const int tid = threadIdx.x;
    const int count = min(bucket_cursor[b], BCAP);
    const int node0 = b << NBITS;
    const unsigned* reg = regions + (size_t)b * BCAP;

    if (tid < 256) {
        int v = (tid < n_buckets) ? min(bucket_cursor[tid], BCAP) : 0;
        int s = incl_scan64(v);
        if ((tid & 63) == 63) bsum[tid >> 6] = s;
        tmp[tid] = s;
    }
    ndeg[tid] = 0;
    __syncthreads();
    if (tid < 256) {
        int wv = tid >> 6;
        int add = (wv > 0 ? bsum[0] : 0) + (wv > 1 ? bsum[1] : 0) + (wv > 2 ? bsum[2] : 0);
        tmp[tid] += add;
    }
    __syncthreads();
    if (tid == 0) {
        s_cbase = b ? tmp[b - 1] : 0;
        if (b == 0) offs4[(size_t)4 * n_nodes] = tmp[255];   // total kept edge count
    }
    __syncthreads();

    for (int k = tid; k < count; k += 1024) {
        unsigned e = reg[k];
        int bin = (int)((e >> 16) << 2) | (int)((e & 0xffffu) >> TSHIFT);
        atomicAdd(&ndeg[bin], 1);
    }
    __syncthreads();
    {
        int v = ndeg[tid];
        int s = incl_scan64(v);
        const int wid = tid >> 6;
        if ((tid & 63) == 63) wsum[wid] = s;
        __syncthreads();
        if (tid < 16) {
            int wv = wsum[tid];
#pragma unroll
            for (int o = 1; o < 16; o <<= 1) {
                int u = __shfl_up(wv, o);
                if (tid >= o) wv += u;
            }
            wsum[tid] = wv;
        }
        __syncthreads();
        const int cbase = s_cbase;
        int excl = s + (wid ? wsum[wid - 1] : 0) - v;
        ncur[tid] = excl;
        if (node0 + (tid >> 2) < n_nodes) offs4[(node0 << 2) + tid] = cbase + excl;
    }
    __syncthreads();
    const int cbase = s_cbase;
    for (int k = tid; k < count; k += 1024) {
        unsigned e = reg[k];
        int bin = (int)((e >> 16) << 2) | (int)((e & 0xffffu) >> TSHIFT);
        int p = atomicAdd(&ncur[bin], 1);
        csr_src[cbase + p] = (int)(e & 0xffffu);
    }
}

// ---- mean aggregation over HALF rows (64 B), L2-resident table ----------
// Half-table = N x 64 B = 3.2 MB < 4 MB per-XCD L2, so the random row
// reads are L2 hits instead of L3 misses. Wave = 16 nodes (q = lane>>2)
// x 4 lanes (l4 = lane&3, 16 B each -> one 64 B line per edge row).
// Two dispatches (half=0,1) keep the live working set to one half-table.
__global__ void __launch_bounds__(256, 8) gather_half_kernel(
        const unsigned* __restrict__ feat8,
        const int* __restrict__ offs4,
        const int* __restrict__ csr_src,
        unsigned* __restrict__ aggf8, int n_nodes, int half) {
    const int wid = (blockIdx.x * blockDim.x + threadIdx.x) >> 6;
    const int lane = threadIdx.x & 63;
    const int q = lane >> 2;       // local node 0..15
    const int l4 = lane & 3;       // 16 B chunk within the 64 B half-row
    const int node = wid * 16 + q;
    if (node - q >= n_nodes) return;   // whole wave out of range
    const int nc = (node < n_nodes) ? node : (n_nodes - 1);
    const unsigned* fb = feat8 + (size_t)half * 16 + (size_t)l4 * 4;
    floatx2 a2[8];
#pragma unroll
    for (int i = 0; i < 8; ++i) a2[i] = (floatx2)(0.f);

    const int beg = offs4[(size_t)4 * nc];
    const int end = offs4[(size_t)4 * nc + 4];
    int e = beg;
    for (; e + 2 <= end; e += 2) {
        int s0 = csr_src[e];
        int s1 = csr_src[e + 1];
        uint4 u0 = *(const uint4*)(fb + (size_t)s0 * 32);
        uint4 u1 = *(const uint4*)(fb + (size_t)s1 * 32);
        accf8p(a2, u0);
        accf8p(a2, u1);
    }
    if (e < end) {
        int s0 = csr_src[e];
        uint4 u0 = *(const uint4*)(fb + (size_t)s0 * 32);
        accf8p(a2, u0);
    }

    float r = 1.0f / fmaxf((float)(end - beg), 1.0f);
    unsigned o[4];
#pragma unroll
    for (int j = 0; j < 4; ++j) {
        int lo = __builtin_amdgcn_cvt_pk_fp8_f32(a2[2 * j].x * r, a2[2 * j].y * r, 0, false);
        o[j] = (unsigned)__builtin_amdgcn_cvt_pk_fp8_f32(a2[2 * j + 1].x * r,
                                                         a2[2 * j + 1].y * r, lo, true);
    }
    if (node < n_nodes) {
        *(uint4*)(aggf8 + (size_t)node * 32 + (size_t)half * 16 + l4 * 4) =
            make_uint4(o[0], o[1], o[2], o[3]);
    }
}

// ---- MFMA GEMM, all-fp8, column-split x2, LDS-staged weights ------------
__global__ void __launch_bounds__(256, 4) mfma_gemm(
        const unsigned* __restrict__ aggf8, const unsigned* __restrict__ xin8,
        const unsigned* __restrict__ Wlt, const unsigned* __restrict__ Wrt,
        const float* __restrict__ bias, unsigned char* __restrict__ outf8,
        float* __restrict__ nrm2, int n_nodes, int relu) {
    __shared__ unsigned sB[2][64 * BSTRIDE8];   // 18.4 KB
    const int tid = threadIdx.x;
    const int wave = tid >> 6;
    const int lane = tid & 63;
    const int li = lane & 15;
    const int quad = lane >> 4;
    const int node0 = blockIdx.x * 64 + wave * 16;
    const int colbase = blockIdx.y * 64;

#pragma unroll
    for (int m = 0; m < 2; ++m) {
        const unsigned* Wsrc = (m ? Wrt : Wlt) + (size_t)colbase * 32;
        for (int i = tid; i < 512; i += 256) {      // 64 cols x 8 uint4
            int col = i >> 3;
            int c4 = (i & 7) * 4;
            uint4 v = *(const uint4*)(Wsrc + col * 32 + c4);
            *(uint4*)(&sB[m][col * BSTRIDE8 + c4]) = v;
        }
    }
    __syncthreads();

    if (node0 >= n_nodes) return;    // tail waves exit AFTER the barrier

    floatx4 acc[4];
#pragma unroll
    for (int t = 0; t < 4; ++t) acc[t] = (floatx4)(0.f);

    int arow = node0 + li;
    if (arow >= n_nodes) arow = n_nodes - 1;   // clamp; stores are guarded
    const unsigned* aptr1 = aggf8 + (size_t)arow * 32 + quad * 2;
    const unsigned* aptr2 = xin8 + (size_t)arow * 32 + quad * 2;
    const unsigned* sb0 = &sB[0][li * BSTRIDE8 + quad * 2];
    const unsigned* sb1 = &sB[1][li * BSTRIDE8 + quad * 2];

#pragma unroll
    for (int ks = 0; ks < 4; ++ks) {               // K=128 -> 4 steps of 32
        long af = *(const long*)(aptr1 + ks * 8);
#pragma unroll
        for (int ct = 0; ct < 4; ++ct) {
            long bf = *(const long*)(sb0 + ct * 16 * BSTRIDE8 + ks * 8);
            acc[ct] = __builtin_amdgcn_mfma_f32_16x16x32_fp8_fp8(af, bf, acc[ct], 0, 0, 0);
        }
    }
#pragma unroll
    for (int ks = 0; ks < 4; ++ks) {               // K=128 -> 4 steps of 32
        long af = *(const long*)(aptr2 + ks * 8);
#pragma unroll
        for (int ct = 0; ct < 4; ++ct) {
            long bf = *(const long*)(sb1 + ct * 16 * BSTRIDE8 + ks * 8);
            acc[ct] = __builtin_amdgcn_mfma_f32_16x16x32_fp8_fp8(af, bf, acc[ct], 0, 0, 0);
        }
    }

    float sq[4] = {0.f, 0.f, 0.f, 0.f};
#pragma unroll
    for (int ct = 0; ct < 4; ++ct) {
        int col = colbase + ct * 16 + li;
        float bv = bias[col];
#pragma unroll
        for (int r = 0; r < 4; ++r) {
            int node = node0 + quad * 4 + r;
            float o = acc[ct][r] + bv;
            if (relu) o = fmaxf(o, 0.f);
            int pk = __builtin_amdgcn_cvt_pk_fp8_f32(o, o, 0, false);
            if (nrm2) {
                floatx2 dq = __builtin_amdgcn_cvt_pk_f32_fp8(pk, false);
                sq[r] += dq.x * dq.x;
            }
            if (node < n_nodes) {
                outf8[(size_t)node * D + col] = (unsigned char)(pk & 0xff);
            }
        }
    }
    if (nrm2) {
#pragma unroll
        for (int r = 0; r < 4; ++r) {
            float s = sq[r];
            s += __shfl_xor(s, 1);
            s += __shfl_xor(s, 2);
            s += __shfl_xor(s, 4);
            s += __shfl_xor(s, 8);
            int node = node0 + quad * 4 + r;
            if (li == 0 && node < n_nodes) unsafeAtomicAdd(&nrm2[node], s);
        }
    }
}

// ---- decode over HALF rows: 4 lanes/pair, partial-dot two-pass ----------
// Each pass's random reads touch only a 3.2 MB half-table (L2-resident).
// half=0 writes partial dot; half=1 adds, normalizes, applies sigmoid.
__global__ void decode_half_kernel(const unsigned* __restrict__ h8,
                                   const float* __restrict__ nrm2,
                                   const int* __restrict__ ia, const int* __restrict__ ib,
                                   float* __restrict__ partial, float* __restrict__ out,
                                   int n_pairs, int half) {
    int t = blockIdx.x * blockDim.x + threadIdx.x;
    int p = t >> 2;
    if (p >= n_pairs) return;
    int l4 = t & 3;
    int i0 = ia[p];
    int i1 = ib[p];
    const unsigned* hb = h8 + (size_t)half * 16 + (size_t)l4 * 4;
    uint4 ua = *(const uint4*)(hb + (size_t)i0 * 32);
    uint4 ub = *(const uint4*)(hb + (size_t)i1 * 32);
    float dot = dotf8(ua, ub);
    dot += __shfl_xor(dot, 1);
    dot += __shfl_xor(dot, 2);
    if (l4 == 0) {
        if (half == 0) {
            partial[p] = dot;
        } else {
            dot += partial[p];
            float denom = fmaxf(sqrtf(nrm2[i0] * nrm2[i1]), 1e-6f);
            float s = dot / denom;
            out[p] = 1.0f / (1.0f + expf(-s));
        }
    }
}

extern "C" void kernel_launch(void* const* d_in, const int* in_sizes, int n_in,
                              void* d_out, int out_size, void* d_ws, size_t ws_size,
                              hipStream_t stream) {
    const float* x   = (const float*)d_in[0];
    const int*   ei  = (const int*)d_in[1];
    const int*   di  = (const int*)d_in[2];
    const float* W1l = (const float*)d_in[3];
    const float* b1  = (const float*)d_in[4];
    const float* W1r = (const float*)d_in[5];
    const float* W2l = (const float*)d_in[6];
    const float* b2  = (const float*)d_in[7];
    const float* W2r = (const float*)d_in[8];

    const int N = in_sizes[0] / D;
    const int E = in_sizes[1] / 2;
    const int K = in_sizes[2] / 2;
    const size_t NQ = (size_t)N * (D / 4);   // u32 count per fp8 feature matrix
    const int NB = (N + 255) >> 8;

    const int* src  = ei;
    const int* dstp = ei + E;
    const int* dia  = di;
    const int* dib  = di + K;

    // ---- workspace layout (u32 units) ----
    int* bucket_cursor = (int*)d_ws;                    // 256 (zeroed in prep)
    float* nrm2        = (float*)(bucket_cursor + 256); // N   (zeroed in prep)
    int* offs4         = (int*)(nrm2 + N);              // 4N+64
    int* csr_src       = offs4 + 4 * N + 64;            // E
    unsigned* xf8      = (unsigned*)(csr_src + E);      // NQ
    unsigned* h1f8     = xf8 + NQ;                      // NQ
    unsigned* h2f8     = h1f8 + NQ;                     // NQ
    unsigned* Wtf8     = h2f8 + NQ;                     // 4 x 4096
    unsigned* regions  = Wtf8 + 16384;                  // NB*BCAP (aggf8 overlays)
    unsigned* aggf8    = regions;                       // NQ <= NB*BCAP
    float* partial     = (float*)regions;               // K floats; decode-time only
    // (aggf8 is dead after the last gemm; K <= NB*BCAP so partial fits.)

    float* out = (float*)d_out;

    // fused prep: fp8 conversions + weight transpose + counter zeroing
    const int nq = (int)NQ;
    const int nblk_a = (nq + 255) / 256;
    const int nblk_b = 64;                 // 4 x 4096 u32
    const int nzero = 256 + N;
    const int nblk_c = (nzero + 255) / 256;
    prep_kernel<<<nblk_a + nblk_b + nblk_c, 256, 0, stream>>>(
        x, xf8, nq, nblk_a, nblk_b, W1l, W1r, W2l, W2r, Wtf8, bucket_cursor, nzero);

    // CSR build
    const int gridA = (E + CHUNK - 1) / CHUNK;
    bucketA_kernel<<<gridA, 512, 0, stream>>>(src, dstp, bucket_cursor, regions, E, NB);
    bucketB_kernel<<<NB, 1024, 0, stream>>>(regions, bucket_cursor, offs4, csr_src, NB, N);

    // gather: 16 nodes/wave, two half-row passes (L2-resident half-tables)
    const int gather_waves = (N + 15) / 16;
    const int gather_blocks = (gather_waves * 64 + 255) / 256;
    const dim3 gemm_grid((N + 63) / 64, 2);

    // layer 1
    gather_half_kernel<<<gather_blocks, 256, 0, stream>>>(xf8, offs4, csr_src, aggf8, N, 0);
    gather_half_kernel<<<gather_blocks, 256, 0, stream>>>(xf8, offs4, csr_src, aggf8, N, 1);
    mfma_gemm<<<gemm_grid, 256, 0, stream>>>(aggf8, xf8, Wtf8, Wtf8 + 4096, b1,
                                             (unsigned char*)h1f8, nullptr, N, 1);

    // layer 2
    gather_half_kernel<<<gather_blocks, 256, 0, stream>>>(h1f8, offs4, csr_src, aggf8, N, 0);
    gather_half_kernel<<<gather_blocks, 256, 0, stream>>>(h1f8, offs4, csr_src, aggf8, N, 1);
    mfma_gemm<<<gemm_grid, 256, 0, stream>>>(aggf8, h1f8, Wtf8 + 8192, Wtf8 + 12288, b2,
                                             (unsigned char*)h2f8, nrm2, N, 0);

    // decode: two half-row passes with partial-dot buffer
    {
        long long threads = (long long)K * 4;
        int blocks = (int)((threads + 255) / 256);
        decode_half_kernel<<<blocks, 256, 0, stream>>>(h2f8, nrm2, dia, dib,
                                                       partial, out, K, 0);
        decode_half_kernel<<<blocks, 256, 0, stream>>>(h2f8, nrm2, dia, dib,
                                                       partial, out, K, 1);
    }
}

// Round 4
// 232.892 us; speedup vs baseline: 5.3766x; 1.1240x over previous
//
#include <hip/hip_runtime.h>
#include <cstddef>

#define D 128
#define NBITS 7            // nodes per bucket = 128 -> 391 buckets for N=50000
#define BCAP2 6144         // per-bucket CSR capacity (mean ~4092, +32 sigma)
#define CHUNK 4096         // edges per bucketA chunk
#define BSTRIDE8 36        // LDS weight-tile stride (u32), proven layout
// NOTE: packing (node_in_bucket<<16)|src into u32 requires N <= 65536 (here N=50000).

typedef float floatx4 __attribute__((ext_vector_type(4)));  // 4 f32
typedef float floatx2 __attribute__((ext_vector_type(2)));  // 2 f32

__device__ __forceinline__ int incl_scan64(int v) {
    const int lane = threadIdx.x & 63;
#pragma unroll
    for (int o = 1; o < 64; o <<= 1) {
        int u = __shfl_up(v, o);
        if (lane >= o) v += u;
    }
    return v;
}

__device__ __forceinline__ void accf8p(floatx2* a2, uint4 u) {
    unsigned w[4] = {u.x, u.y, u.z, u.w};
#pragma unroll
    for (int k = 0; k < 4; ++k) {
        a2[2 * k + 0] += __builtin_amdgcn_cvt_pk_f32_fp8((int)w[k], false);
        a2[2 * k + 1] += __builtin_amdgcn_cvt_pk_f32_fp8((int)w[k], true);
    }
}

__device__ __forceinline__ float dotf8(uint4 ua, uint4 ub) {
    unsigned wa[4] = {ua.x, ua.y, ua.z, ua.w};
    unsigned wb[4] = {ub.x, ub.y, ub.z, ub.w};
    float dot = 0.f;
#pragma unroll
    for (int k = 0; k < 4; ++k) {
        floatx2 alo = __builtin_amdgcn_cvt_pk_f32_fp8((int)wa[k], false);
        floatx2 ahi = __builtin_amdgcn_cvt_pk_f32_fp8((int)wa[k], true);
        floatx2 blo = __builtin_amdgcn_cvt_pk_f32_fp8((int)wb[k], false);
        floatx2 bhi = __builtin_amdgcn_cvt_pk_f32_fp8((int)wb[k], true);
        dot = fmaf(alo.x, blo.x, dot);
        dot = fmaf(alo.y, blo.y, dot);
        dot = fmaf(ahi.x, bhi.x, dot);
        dot = fmaf(ahi.y, bhi.y, dot);
    }
    return dot;
}

// =====================================================================
// K1: fused prep (x->fp8, W->Wt fp8) + chunk-local bucketize.
// No zero-init requirements anywhere: chunk scheme is write-only,
// nrm2 is plain-stored by K3 (single writer). 4-launch pipeline total.
// =====================================================================
__global__ void __launch_bounds__(256) k1_prep_bucket(
        const float* __restrict__ x, unsigned* __restrict__ xf8,
        int nq, int nblk_a,
        const float* __restrict__ W1l, const float* __restrict__ W1r,
        const float* __restrict__ W2l, const float* __restrict__ W2r,
        unsigned* __restrict__ Wtf8,
        const int* __restrict__ src, const int* __restrict__ dst, int n_edges,
        unsigned* __restrict__ chunk_data, int* __restrict__ chunk_off,
        int nbuck) {
    int blk = (int)blockIdx.x;
    const int tid = threadIdx.x;
    if (blk < nblk_a) {
        int t = blk * 256 + tid;
        if (t < nq) {
            float4 v = ((const float4*)x)[t];
            int lo = __builtin_amdgcn_cvt_pk_fp8_f32(v.x, v.y, 0, false);
            xf8[t] = (unsigned)__builtin_amdgcn_cvt_pk_fp8_f32(v.z, v.w, lo, true);
        }
        return;
    }
    blk -= nblk_a;
    if (blk < 64) {
        int t2 = blk * 256 + tid;     // 0..16383
        int widx = t2 >> 12;
        int within = t2 & 4095;
        int n = within >> 5;          // output col 0..127
        int g = within & 31;          // k-group of 4
        const float* W = (widx == 0) ? W1l : (widx == 1) ? W1r : (widx == 2) ? W2l : W2r;
        float w0 = W[(size_t)(4 * g + 0) * D + n];
        float w1 = W[(size_t)(4 * g + 1) * D + n];
        float w2 = W[(size_t)(4 * g + 2) * D + n];
        float w3 = W[(size_t)(4 * g + 3) * D + n];
        int lo = __builtin_amdgcn_cvt_pk_fp8_f32(w0, w1, 0, false);
        Wtf8[(size_t)widx * 4096 + (size_t)n * 32 + g] =
            (unsigned)__builtin_amdgcn_cvt_pk_fp8_f32(w2, w3, lo, true);
        return;
    }
    blk -= 64;
    // ---- bucketA: chunk-local sort of CHUNK edges by bucket ----
    __shared__ int cnt[512];
    __shared__ int cur[512];
    __shared__ int wsum[4];
    __shared__ unsigned ent[CHUNK];
    const int c = blk;
    const int e0 = c * CHUNK;
    const int n = min(CHUNK, n_edges - e0);
    cnt[tid] = 0;
    cnt[tid + 256] = 0;
    __syncthreads();
    for (int i = tid; i < n; i += 256)
        atomicAdd(&cnt[dst[e0 + i] >> NBITS], 1);
    __syncthreads();
    // exclusive scan over 512 buckets, 2 per thread
    int c0 = cnt[2 * tid], c1 = cnt[2 * tid + 1];
    int v = c0 + c1;
    int s = incl_scan64(v);
    if ((tid & 63) == 63) wsum[tid >> 6] = s;
    __syncthreads();
    {
        int wv = tid >> 6;
        int add = (wv > 0 ? wsum[0] : 0) + (wv > 1 ? wsum[1] : 0) + (wv > 2 ? wsum[2] : 0);
        int excl = s + add - v;
        cur[2 * tid] = excl;
        cur[2 * tid + 1] = excl + c0;
        const int stride = nbuck + 1;
        if (2 * tid <= nbuck) chunk_off[(size_t)c * stride + 2 * tid] = excl;
        if (2 * tid + 1 <= nbuck) chunk_off[(size_t)c * stride + 2 * tid + 1] = excl + c0;
    }
    __syncthreads();
    for (int i = tid; i < n; i += 256) {
        int d = dst[e0 + i];
        int sv = src[e0 + i];
        int b = d >> NBITS;
        int p = atomicAdd(&cur[b], 1);
        ent[p] = ((unsigned)(d & ((1 << NBITS) - 1)) << 16) | (unsigned)sv;
    }
    __syncthreads();
    for (int i = tid; i < n; i += 256) chunk_data[(size_t)e0 + i] = ent[i];
}

// =====================================================================
// K2: per-bucket CSR build (from chunk slices) + gather + layer-1 GEMM.
// Block = bucket b = 128 nodes, 512 threads (8 waves).
// =====================================================================
__global__ void __launch_bounds__(512, 4) k2_layer1(
        const unsigned* __restrict__ chunk_data, const int* __restrict__ chunk_off,
        int nchunk, int nbuck,
        const unsigned* __restrict__ xf8, const unsigned* __restrict__ Wt,
        const float* __restrict__ bias,
        unsigned* __restrict__ csr16g, int* __restrict__ offsG,
        unsigned* __restrict__ aggf8, unsigned char* __restrict__ h1,
        int n_nodes) {
    __shared__ unsigned sB[2][128 * BSTRIDE8];   // 36.9 KB
    __shared__ unsigned short lcsr[BCAP2];       // 12.3 KB
    __shared__ int ndeg[128], ncur[128], offs_l[130];
    __shared__ int s_w0;
    const int tid = threadIdx.x;
    const int b = blockIdx.x;
    const int stride = nbuck + 1;

    if (tid < 128) ndeg[tid] = 0;
    __syncthreads();

    // histogram over this bucket's chunk slices
    const int w = tid >> 1, half = tid & 1;
    for (int c = w; c < nchunk; c += 256) {
        int beg = chunk_off[(size_t)c * stride + b];
        int end = chunk_off[(size_t)c * stride + b + 1];
        const unsigned* cd = chunk_data + (size_t)c * CHUNK;
        for (int i = beg + half; i < end; i += 2)
            atomicAdd(&ndeg[cd[i] >> 16], 1);
    }
    __syncthreads();
    int v = 0, s = 0;
    if (tid < 128) {
        v = ndeg[tid];
        s = incl_scan64(v);
        if (tid == 63) s_w0 = s;
    }
    __syncthreads();
    if (tid < 128) {
        if (tid >= 64) s += s_w0;
        int excl = min(s - v, BCAP2);
        ncur[tid] = excl;
        offs_l[tid] = excl;
        offsG[(size_t)b * 129 + tid] = excl;
        if (tid == 127) {
            int tot = min(s, BCAP2);
            offs_l[128] = tot;
            offsG[(size_t)b * 129 + 128] = tot;
        }
    }
    __syncthreads();
    // scatter into LDS csr (u16 src ids)
    for (int c = w; c < nchunk; c += 256) {
        int beg = chunk_off[(size_t)c * stride + b];
        int end = chunk_off[(size_t)c * stride + b + 1];
        const unsigned* cd = chunk_data + (size_t)c * CHUNK;
        for (int i = beg + half; i < end; i += 2) {
            unsigned e = cd[i];
            int pos = atomicAdd(&ncur[e >> 16], 1);
            if (pos < BCAP2) lcsr[pos] = (unsigned short)(e & 0xffffu);
        }
    }
    // stage weight tiles (independent of lcsr/scratch; barrier below covers both)
    for (int i = tid; i < 2048; i += 512) {
        int m = i >> 10;
        int col = (i >> 3) & 127;
        int c4 = (i & 7) * 4;
        *(uint4*)&sB[m][col * BSTRIDE8 + c4] =
            *(const uint4*)(Wt + (size_t)m * 4096 + (size_t)col * 32 + c4);
    }
    __syncthreads();
    // persist csr for K3 (u16 pairs as u32)
    {
        int tot = offs_l[128];
        int words = (tot + 1) >> 1;
        const unsigned* l32 = (const unsigned*)lcsr;
        for (int i = tid; i < words; i += 512)
            csr16g[(size_t)b * (BCAP2 / 2) + i] = l32[i];
    }
    // ---- gather: 8 waves x 8 nodes, 2 passes, full 128B rows ----
    const int wv2 = tid >> 6;
    const int lane = tid & 63;
    const int q = lane >> 3;
    const int l8 = lane & 7;
    const unsigned* fb = xf8 + (size_t)l8 * 4;
#pragma unroll
    for (int pass = 0; pass < 2; ++pass) {
        const int nl = pass * 64 + wv2 * 8 + q;
        const int beg = offs_l[nl];
        const int end = offs_l[nl + 1];
        floatx2 a2[8];
#pragma unroll
        for (int i = 0; i < 8; ++i) a2[i] = (floatx2)(0.f);
        int e = beg;
        for (; e + 2 <= end; e += 2) {
            int s0 = lcsr[e];
            int s1 = lcsr[e + 1];
            uint4 u0 = *(const uint4*)(fb + (size_t)s0 * 32);
            uint4 u1 = *(const uint4*)(fb + (size_t)s1 * 32);
            accf8p(a2, u0);
            accf8p(a2, u1);
        }
        if (e < end) {
            int s0 = lcsr[e];
            uint4 u0 = *(const uint4*)(fb + (size_t)s0 * 32);
            accf8p(a2, u0);
        }
        float r = 1.0f / fmaxf((float)(end - beg), 1.0f);
        unsigned o[4];
#pragma unroll
        for (int j = 0; j < 4; ++j) {
            int lo = __builtin_amdgcn_cvt_pk_fp8_f32(a2[2 * j].x * r, a2[2 * j].y * r, 0, false);
            o[j] = (unsigned)__builtin_amdgcn_cvt_pk_fp8_f32(a2[2 * j + 1].x * r,
                                                             a2[2 * j + 1].y * r, lo, true);
        }
        const int node = b * 128 + nl;
        if (node < n_nodes)
            *(uint4*)(aggf8 + (size_t)node * 32 + l8 * 4) = make_uint4(o[0], o[1], o[2], o[3]);
    }
    __syncthreads();   // drains vmem: aggf8 visible to this block's gemm reads

    // ---- GEMM: wave wv2 handles 16 nodes x 128 cols ----
    const int li = lane & 15;
    const int quad = lane >> 4;
    const int node0 = b * 128 + wv2 * 16;
    if (node0 >= n_nodes) return;

    floatx4 acc[8];
#pragma unroll
    for (int t = 0; t < 8; ++t) acc[t] = (floatx4)(0.f);

    int arow = node0 + li;
    if (arow >= n_nodes) arow = n_nodes - 1;   // clamp; stores guarded
    const unsigned* aptr1 = aggf8 + (size_t)arow * 32 + quad * 2;
    const unsigned* aptr2 = xf8 + (size_t)arow * 32 + quad * 2;
    const unsigned* sb0 = &sB[0][li * BSTRIDE8 + quad * 2];
    const unsigned* sb1 = &sB[1][li * BSTRIDE8 + quad * 2];

#pragma unroll
    for (int ks = 0; ks < 4; ++ks) {
        long af = *(const long*)(aptr1 + ks * 8);
#pragma unroll
        for (int ct = 0; ct < 8; ++ct) {
            long bf = *(const long*)(sb0 + ct * 16 * BSTRIDE8 + ks * 8);
            acc[ct] = __builtin_amdgcn_mfma_f32_16x16x32_fp8_fp8(af, bf, acc[ct], 0, 0, 0);
        }
    }
#pragma unroll
    for (int ks = 0; ks < 4; ++ks) {
        long af = *(const long*)(aptr2 + ks * 8);
#pragma unroll
        for (int ct = 0; ct < 8; ++ct) {
            long bf = *(const long*)(sb1 + ct * 16 * BSTRIDE8 + ks * 8);
            acc[ct] = __builtin_amdgcn_mfma_f32_16x16x32_fp8_fp8(af, bf, acc[ct], 0, 0, 0);
        }
    }
#pragma unroll
    for (int ct = 0; ct < 8; ++ct) {
        int col = ct * 16 + li;
        float bv = bias[col];
#pragma unroll
        for (int r = 0; r < 4; ++r) {
            int node = node0 + quad * 4 + r;
            float o = acc[ct][r] + bv;
            o = fmaxf(o, 0.f);    // relu (layer 1)
            int pk = __builtin_amdgcn_cvt_pk_fp8_f32(o, o, 0, false);
            if (node < n_nodes)
                h1[(size_t)node * D + col] = (unsigned char)(pk & 0xff);
        }
    }
}

// =====================================================================
// K3: gather(h1) + layer-2 GEMM + nrm2 (single-writer plain store).
// =====================================================================
__global__ void __launch_bounds__(512, 4) k3_layer2(
        const int* __restrict__ offsG, const unsigned* __restrict__ csr16g,
        const unsigned* __restrict__ h1f8, const unsigned* __restrict__ Wt2,
        const float* __restrict__ bias,
        unsigned* __restrict__ aggf8, unsigned char* __restrict__ h2,
        float* __restrict__ nrm2, int n_nodes) {
    __shared__ unsigned sB[2][128 * BSTRIDE8];
    __shared__ int offs_l[130];
    const int tid = threadIdx.x;
    const int b = blockIdx.x;
    if (tid < 129) offs_l[tid] = offsG[(size_t)b * 129 + tid];
    for (int i = tid; i < 2048; i += 512) {
        int m = i >> 10;
        int col = (i >> 3) & 127;
        int c4 = (i & 7) * 4;
        *(uint4*)&sB[m][col * BSTRIDE8 + c4] =
            *(const uint4*)(Wt2 + (size_t)m * 4096 + (size_t)col * 32 + c4);
    }
    __syncthreads();

    const unsigned short* csr = (const unsigned short*)csr16g + (size_t)b * BCAP2;
    const int wv2 = tid >> 6;
    const int lane = tid & 63;
    const int q = lane >> 3;
    const int l8 = lane & 7;
    const unsigned* fb = h1f8 + (size_t)l8 * 4;
#pragma unroll
    for (int pass = 0; pass < 2; ++pass) {
        const int nl = pass * 64 + wv2 * 8 + q;
        const int beg = offs_l[nl];
        const int end = offs_l[nl + 1];
        floatx2 a2[8];
#pragma unroll
        for (int i = 0; i < 8; ++i) a2[i] = (floatx2)(0.f);
        int e = beg;
        for (; e + 2 <= end; e += 2) {
            int s0 = csr[e];
            int s1 = csr[e + 1];
            uint4 u0 = *(const uint4*)(fb + (size_t)s0 * 32);
            uint4 u1 = *(const uint4*)(fb + (size_t)s1 * 32);
            accf8p(a2, u0);
            accf8p(a2, u1);
        }
        if (e < end) {
            int s0 = csr[e];
            uint4 u0 = *(const uint4*)(fb + (size_t)s0 * 32);
            accf8p(a2, u0);
        }
        float r = 1.0f / fmaxf((float)(end - beg), 1.0f);
        unsigned o[4];
#pragma unroll
        for (int j = 0; j < 4; ++j) {
            int lo = __builtin_amdgcn_cvt_pk_fp8_f32(a2[2 * j].x * r, a2[2 * j].y * r, 0, false);
            o[j] = (unsigned)__builtin_amdgcn_cvt_pk_fp8_f32(a2[2 * j + 1].x * r,
                                                             a2[2 * j + 1].y * r, lo, true);
        }
        const int node = b * 128 + nl;
        if (node < n_nodes)
            *(uint4*)(aggf8 + (size_t)node * 32 + l8 * 4) = make_uint4(o[0], o[1], o[2], o[3]);
    }
    __syncthreads();

    const int li = lane & 15;
    const int quad = lane >> 4;
    const int node0 = b * 128 + wv2 * 16;
    if (node0 >= n_nodes) return;

    floatx4 acc[8];
#pragma unroll
    for (int t = 0; t < 8; ++t) acc[t] = (floatx4)(0.f);

    int arow = node0 + li;
    if (arow >= n_nodes) arow = n_nodes - 1;
    const unsigned* aptr1 = aggf8 + (size_t)arow * 32 + quad * 2;
    const unsigned* aptr2 = h1f8 + (size_t)arow * 32 + quad * 2;
    const unsigned* sb0 = &sB[0][li * BSTRIDE8 + quad * 2];
    const unsigned* sb1 = &sB[1][li * BSTRIDE8 + quad * 2];

#pragma unroll
    for (int ks = 0; ks < 4; ++ks) {
        long af = *(const long*)(aptr1 + ks * 8);
#pragma unroll
        for (int ct = 0; ct < 8; ++ct) {
            long bf = *(const long*)(sb0 + ct * 16 * BSTRIDE8 + ks * 8);
            acc[ct] = __builtin_amdgcn_mfma_f32_16x16x32_fp8_fp8(af, bf, acc[ct], 0, 0, 0);
        }
    }
#pragma unroll
    for (int ks = 0; ks < 4; ++ks) {
        long af = *(const long*)(aptr2 + ks * 8);
#pragma unroll
        for (int ct = 0; ct < 8; ++ct) {
            long bf = *(const long*)(sb1 + ct * 16 * BSTRIDE8 + ks * 8);
            acc[ct] = __builtin_amdgcn_mfma_f32_16x16x32_fp8_fp8(af, bf, acc[ct], 0, 0, 0);
        }
    }
    float sq[4] = {0.f, 0.f, 0.f, 0.f};
#pragma unroll
    for (int ct = 0; ct < 8; ++ct) {
        int col = ct * 16 + li;
        float bv = bias[col];
#pragma unroll
        for (int r = 0; r < 4; ++r) {
            int node = node0 + quad * 4 + r;
            float o = acc[ct][r] + bv;
            int pk = __builtin_amdgcn_cvt_pk_fp8_f32(o, o, 0, false);
            floatx2 dq = __builtin_amdgcn_cvt_pk_f32_fp8(pk, false);
            sq[r] += dq.x * dq.x;
            if (node < n_nodes)
                h2[(size_t)node * D + col] = (unsigned char)(pk & 0xff);
        }
    }
#pragma unroll
    for (int r = 0; r < 4; ++r) {
        float sv = sq[r];
        sv += __shfl_xor(sv, 1);
        sv += __shfl_xor(sv, 2);
        sv += __shfl_xor(sv, 4);
        sv += __shfl_xor(sv, 8);
        int node = node0 + quad * 4 + r;
        if (li == 0 && node < n_nodes) nrm2[node] = sv;   // single writer
    }
}

// =====================================================================
// K4: decode, 8 lanes/pair, fp8 rows
// =====================================================================
__global__ void decode_kernel(const unsigned* __restrict__ h8, const float* __restrict__ nrm2,
                              const int* __restrict__ ia, const int* __restrict__ ib,
                              float* __restrict__ out, int n_pairs) {
    int t = blockIdx.x * blockDim.x + threadIdx.x;
    int p = t >> 3;
    if (p >= n_pairs) return;
    int l8 = t & 7;
    int i0 = ia[p];
    int i1 = ib[p];
    uint4 ua = *(const uint4*)(h8 + (size_t)i0 * 32 + l8 * 4);
    uint4 ub = *(const uint4*)(h8 + (size_t)i1 * 32 + l8 * 4);
    float dot = dotf8(ua, ub);
    dot += __shfl_xor(dot, 1);
    dot += __shfl_xor(dot, 2);
    dot += __shfl_xor(dot, 4);
    if (l8 == 0) {
        float denom = fmaxf(sqrtf(nrm2[i0] * nrm2[i1]), 1e-6f);
        float s = dot / denom;
        out[p] = 1.0f / (1.0f + expf(-s));
    }
}

// =====================================================================

extern "C" void kernel_launch(void* const* d_in, const int* in_sizes, int n_in,
                              void* d_out, int out_size, void* d_ws, size_t ws_size,
                              hipStream_t stream) {
    const float* x   = (const float*)d_in[0];
    const int*   ei  = (const int*)d_in[1];
    const int*   di  = (const int*)d_in[2];
    const float* W1l = (const float*)d_in[3];
    const float* b1  = (const float*)d_in[4];
    const float* W1r = (const float*)d_in[5];
    const float* W2l = (const float*)d_in[6];
    const float* b2  = (const float*)d_in[7];
    const float* W2r = (const float*)d_in[8];

    const int N = in_sizes[0] / D;
    const int E = in_sizes[1] / 2;
    const int K = in_sizes[2] / 2;
    const size_t NQ = (size_t)N * (D / 4);   // u32 per fp8 feature matrix
    const int NBUCK = (N + (1 << NBITS) - 1) >> NBITS;     // 391
    const int NCHUNK = (E + CHUNK - 1) / CHUNK;            // 391

    const int* src  = ei;
    const int* dstp = ei + E;
    const int* dia  = di;
    const int* dib  = di + K;

    // ---- workspace layout (u32 units) ----
    unsigned* ws         = (unsigned*)d_ws;
    unsigned* chunk_data = ws;                                   // E
    int*      chunk_off  = (int*)(chunk_data + E);               // NCHUNK*(NBUCK+1)
    unsigned* csr16g     = (unsigned*)(chunk_off + (size_t)NCHUNK * (NBUCK + 1)); // NBUCK*BCAP2/2
    int*      offsG      = (int*)(csr16g + (size_t)NBUCK * (BCAP2 / 2));          // NBUCK*129
    float*    nrm2       = (float*)(offsG + (size_t)NBUCK * 129);                 // N
    unsigned* Wtf8       = (unsigned*)(nrm2 + N);                // 4 x 4096
    unsigned* xf8        = Wtf8 + 16384;                         // NQ
    unsigned* h1f8       = xf8 + NQ;                             // NQ
    unsigned* h2f8       = h1f8 + NQ;                            // NQ
    unsigned* aggf8      = h2f8 + NQ;                            // NQ

    float* out = (float*)d_out;

    const int nq = (int)NQ;
    const int nblk_a = (nq + 255) / 256;

    // K1: prep + chunk bucketize
    k1_prep_bucket<<<nblk_a + 64 + NCHUNK, 256, 0, stream>>>(
        x, xf8, nq, nblk_a, W1l, W1r, W2l, W2r, Wtf8,
        src, dstp, E, chunk_data, chunk_off, NBUCK);

    // K2: CSR + gather + layer-1 GEMM
    k2_layer1<<<NBUCK, 512, 0, stream>>>(
        chunk_data, chunk_off, NCHUNK, NBUCK, xf8, Wtf8, b1,
        csr16g, offsG, aggf8, (unsigned char*)h1f8, N);

    // K3: gather + layer-2 GEMM + nrm2
    k3_layer2<<<NBUCK, 512, 0, stream>>>(
        offsG, csr16g, h1f8, Wtf8 + 8192, b2,
        aggf8, (unsigned char*)h2f8, nrm2, N);

    // K4: decode
    {
        long long threads = (long long)K * 8;
        int blocks = (int)((threads + 255) / 256);
        decode_kernel<<<blocks, 256, 0, stream>>>(h2f8, nrm2, dia, dib, out, K);
    }
}